// Round 3
// baseline (832.979 us; speedup 1.0000x reference)
//
#include <hip/hip_runtime.h>

// GCN layer: out = relu( (1/max(deg,1)) * segsum_dst(order * (hW)[src]) + b )
// h: [100000,64] f32, src/dst: [1.6M] i32, order: [1.6M] f32, W: [64,32], b: [32]
// out: [100000,32] f32

constexpr int N_NODES = 100000;
constexpr int N_EDGES = 1600000;
constexpr int IN_F    = 64;
constexpr int OUT_F   = 32;

#ifndef __has_builtin
#define __has_builtin(x) 0
#endif

// Packed 2xf32 atomic add (global_atomic_pk_add_f32, gfx90a+). Guarded: if the
// toolchain lacks the builtin, fall back to 2 scalar HW atomics
// (unsafeAtomicAdd always lowers to global_atomic_add_f32, never a CAS loop).
#if __has_builtin(__builtin_amdgcn_global_atomic_fadd_v2f32)
#define HAVE_PK_FADD 1
typedef float v2f __attribute__((ext_vector_type(2)));
#endif

__device__ __forceinline__ void atomic_add2(float* p, float x, float y) {
#ifdef HAVE_PK_FADD
    typedef __attribute__((address_space(1))) v2f gv2f;
    v2f v = {x, y};
    __builtin_amdgcn_global_atomic_fadd_v2f32((gv2f*)(void*)p, v);
#else
    unsafeAtomicAdd(p, x);
    unsafeAtomicAdd(p + 1, y);
#endif
}

// ---------------- hw = h @ W  (100000x64 @ 64x32), fused agg/deg zeroing ----------------
// 8 rows per block, one thread per output element. W + h-rows staged in LDS.
// Each block also zeroes a grid-stride slice of agg+deg (ws is poisoned 0xAA
// before every timed call). Legal fusion: edge_scatter is stream-ordered after
// this kernel, so all zeroing completes before any atomic lands.
__global__ __launch_bounds__(256) void gemm64x32_zero(const float* __restrict__ h,
                                                      const float* __restrict__ W,
                                                      float* __restrict__ hw,
                                                      float4* __restrict__ zbase,
                                                      int nz4) {
    __shared__ float Ws[IN_F * OUT_F];   // 8 KB
    __shared__ float hs[8 * IN_F];       // 2 KB
    const int tid = threadIdx.x;

    #pragma unroll
    for (int i = tid; i < IN_F * OUT_F; i += 256) Ws[i] = W[i];

    const int rowBase = blockIdx.x * 8;          // 12500 blocks, N divisible by 8
    ((float2*)hs)[tid] = ((const float2*)(h + (size_t)rowBase * IN_F))[tid];

    // zero agg+deg while the LDS stores land (no dependency on Ws/hs)
    const int zstride = gridDim.x * blockDim.x;
    for (int i = blockIdx.x * blockDim.x + tid; i < nz4; i += zstride)
        zbase[i] = make_float4(0.f, 0.f, 0.f, 0.f);

    __syncthreads();

    const int rl = tid >> 5;   // local row 0..7
    const int f  = tid & 31;   // output feature
    float sum = 0.f;
    #pragma unroll
    for (int k = 0; k < IN_F; ++k)
        sum = fmaf(hs[rl * IN_F + k], Ws[k * OUT_F + f], sum);

    hw[(size_t)rowBase * OUT_F + tid] = sum;     // fully coalesced
}

// ---------------- edge scatter: agg[dst] += order * hw[src]; deg[dst] += 1 ----------------
// (edge, feat-quad) decomposition: 8 threads per edge, each does one float4
// gather (the 8 threads cover the edge's contiguous 128B row) + 2 packed atomics.
__global__ __launch_bounds__(256) void edge_scatter(const int*   __restrict__ src,
                                                    const int*   __restrict__ dst,
                                                    const float* __restrict__ ord,
                                                    const float* __restrict__ hw,
                                                    float*       __restrict__ agg,
                                                    float*       __restrict__ deg) {
    const int total  = N_EDGES * 8;
    const int stride = gridDim.x * blockDim.x;
    for (int i = blockIdx.x * blockDim.x + threadIdx.x; i < total; i += stride) {
        const int e = i >> 3;
        const int q = i & 7;
        const int s = src[e];
        const int d = dst[e];
        const float o = ord[e];
        const float4 v = *(const float4*)(hw + (size_t)s * OUT_F + q * 4);
        float* ap = agg + (size_t)d * OUT_F + q * 4;
        atomic_add2(ap + 0, o * v.x, o * v.y);
        atomic_add2(ap + 2, o * v.z, o * v.w);
        if (q == 0) unsafeAtomicAdd(deg + d, 1.0f);
    }
}

// ---------------- finalize: out = relu(agg * (1/max(deg,1)) + b) ----------------
__global__ __launch_bounds__(256) void finalize(const float* __restrict__ agg,
                                                const float* __restrict__ deg,
                                                const float* __restrict__ b,
                                                float* __restrict__ out) {
    const int total  = N_NODES * 8;   // one float4 per thread
    const int stride = gridDim.x * blockDim.x;
    for (int i = blockIdx.x * blockDim.x + threadIdx.x; i < total; i += stride) {
        const int n  = i >> 3;
        const int f4 = (i & 7) * 4;
        const float dg   = deg[n];
        const float norm = 1.0f / fmaxf(dg, 1.0f);
        const float4 v  = *(const float4*)(agg + (size_t)n * OUT_F + f4);
        const float4 bb = *(const float4*)(b + f4);
        float4 r;
        r.x = fmaxf(fmaf(v.x, norm, bb.x), 0.f);
        r.y = fmaxf(fmaf(v.y, norm, bb.y), 0.f);
        r.z = fmaxf(fmaf(v.z, norm, bb.z), 0.f);
        r.w = fmaxf(fmaf(v.w, norm, bb.w), 0.f);
        *(float4*)(out + (size_t)n * OUT_F + f4) = r;
    }
}

extern "C" void kernel_launch(void* const* d_in, const int* in_sizes, int n_in,
                              void* d_out, int out_size, void* d_ws, size_t ws_size,
                              hipStream_t stream) {
    const float* h   = (const float*)d_in[0];
    const int*   src = (const int*)  d_in[1];
    const int*   dst = (const int*)  d_in[2];
    const float* ord = (const float*)d_in[3];
    const float* W   = (const float*)d_in[4];
    const float* b   = (const float*)d_in[5];
    float*       out = (float*)d_out;

    // ws layout: agg [N*32] | deg [N] | hw [N*32]   (~26 MB total)
    float* ws  = (float*)d_ws;
    float* agg = ws;
    float* deg = ws + (size_t)N_NODES * OUT_F;
    float* hw  = ws + (size_t)N_NODES * (OUT_F + 1);

    const int nz4 = N_NODES * (OUT_F + 1) / 4;  // 825000 float4 (agg+deg)

    // 1) hw = h @ W, fused zeroing of agg+deg
    hipLaunchKernelGGL(gemm64x32_zero, dim3(N_NODES / 8), dim3(256), 0, stream,
                       h, W, hw, (float4*)ws, nz4);

    // 2) scatter messages + degree
    hipLaunchKernelGGL(edge_scatter, dim3(8192), dim3(256), 0, stream,
                       src, dst, ord, hw, agg, deg);

    // 3) normalize + bias + relu
    hipLaunchKernelGGL(finalize, dim3(N_NODES * 8 / 256), dim3(256), 0, stream,
                       agg, deg, b, out);
}

// Round 4
// 380.862 us; speedup vs baseline: 2.1871x; 2.1871x over previous
//
#include <hip/hip_runtime.h>

// GCN layer: out = relu( (1/max(deg,1)) * segsum_dst(order * (hW)[src]) + b )
// h: [100000,64] f32, src/dst: [1.6M] i32, order: [1.6M] f32, W: [64,32], b: [32]
// out: [100000,32] f32
//
// Strategy (round 4): device-scope fp atomics measured at ~37.7G/s with 32B
// memory-side write per atomic (850MB WRITE_SIZE, 722us). Replace 27.2M fp
// atomics with 3.2M int atomics: build CSR buckets (count -> alloc -> bin),
// then gather+finalize per node with plain reads and register accumulation.

constexpr int N_NODES = 100000;
constexpr int N_EDGES = 1600000;
constexpr int IN_F    = 64;
constexpr int OUT_F   = 32;

// ---------------- k1: hw = h @ W, fused zeroing of counts + gcur ----------------
__global__ __launch_bounds__(256) void gemm64x32_zero(const float* __restrict__ h,
                                                      const float* __restrict__ W,
                                                      float* __restrict__ hw,
                                                      int* __restrict__ counts,
                                                      int* __restrict__ gcur) {
    __shared__ float Ws[IN_F * OUT_F];   // 8 KB
    __shared__ float hs[8 * IN_F];       // 2 KB
    const int tid = threadIdx.x;

    #pragma unroll
    for (int i = tid; i < IN_F * OUT_F; i += 256) Ws[i] = W[i];

    const int rowBase = blockIdx.x * 8;          // 12500 blocks, N divisible by 8
    ((float2*)hs)[tid] = ((const float2*)(h + (size_t)rowBase * IN_F))[tid];

    // zero counts while LDS stores land (stream-ordered before k_count)
    const int zstride = gridDim.x * 256;
    for (int i = blockIdx.x * 256 + tid; i < N_NODES; i += zstride) counts[i] = 0;
    if (blockIdx.x == 0 && tid == 0) *gcur = 0;

    __syncthreads();

    const int rl = tid >> 5;   // local row 0..7
    const int f  = tid & 31;   // output feature
    float sum = 0.f;
    #pragma unroll
    for (int k = 0; k < IN_F; ++k)
        sum = fmaf(hs[rl * IN_F + k], Ws[k * OUT_F + f], sum);

    hw[(size_t)rowBase * OUT_F + tid] = sum;     // fully coalesced
}

// ---------------- k2: degree histogram ----------------
__global__ __launch_bounds__(256) void k_count(const int* __restrict__ dst,
                                               int* __restrict__ counts) {
    const int i = blockIdx.x * 256 + threadIdx.x;   // grid = 6250 exact
    if (i < N_EDGES) atomicAdd(&counts[dst[i]], 1);
}

// ---------------- k3: allocate bucket ranges (block scan + 1 atomic/block) ----------------
__global__ __launch_bounds__(1024) void k_alloc(const int* __restrict__ counts,
                                                int* __restrict__ offs,
                                                int* __restrict__ gcur) {
    __shared__ int wsum[16];
    __shared__ int sbase;
    const int i    = blockIdx.x * 1024 + threadIdx.x;
    const int lane = threadIdx.x & 63;
    const int wid  = threadIdx.x >> 6;

    const int c = (i < N_NODES) ? counts[i] : 0;
    // wave-inclusive scan
    int s = c;
    #pragma unroll
    for (int d = 1; d < 64; d <<= 1) {
        int t = __shfl_up(s, d);
        if (lane >= d) s += t;
    }
    if (lane == 63) wsum[wid] = s;
    __syncthreads();
    if (wid == 0) {
        int w = (lane < 16) ? wsum[lane] : 0;
        #pragma unroll
        for (int d = 1; d < 16; d <<= 1) {
            int t = __shfl_up(w, d);
            if (lane >= d) w += t;
        }
        if (lane < 16) wsum[lane] = w;               // inclusive wave totals
        if (lane == 15) sbase = atomicAdd(gcur, w);  // block base
    }
    __syncthreads();
    const int waveExcl = (wid == 0) ? 0 : wsum[wid - 1];
    if (i < N_NODES) offs[i] = sbase + waveExcl + (s - c);   // bucket start
}

// ---------------- k4: bin edge ids into buckets ----------------
// post-increments offs[d]; after this kernel offs[n] == END of bucket n.
__global__ __launch_bounds__(256) void k_bin(const int* __restrict__ dst,
                                             int* __restrict__ offs,
                                             int* __restrict__ bucket) {
    const int i = blockIdx.x * 256 + threadIdx.x;   // grid = 6250 exact
    if (i < N_EDGES) {
        const int pos = atomicAdd(&offs[dst[i]], 1);
        bucket[pos] = i;
    }
}

// ---------------- k5: gather + normalize + bias + relu ----------------
// 8 threads per node, one float4 of features each. Register accumulation,
// no atomics. Independent next-iteration loads -> compiler can pipeline.
__global__ __launch_bounds__(256) void k_gather(const int* __restrict__ bucket,
                                                const int* __restrict__ offs,
                                                const int* __restrict__ counts,
                                                const int* __restrict__ src,
                                                const float* __restrict__ ord,
                                                const float* __restrict__ hw,
                                                const float* __restrict__ b,
                                                float* __restrict__ out) {
    const int i = blockIdx.x * 256 + threadIdx.x;   // 3125*256 = 800000 exact
    const int n = i >> 3;
    const int q = i & 7;

    const int deg   = counts[n];
    const int end   = offs[n];        // after k_bin: end of bucket
    const int start = end - deg;

    float4 acc = make_float4(0.f, 0.f, 0.f, 0.f);
    for (int j = start; j < end; ++j) {
        const int   e = bucket[j];
        const float o = ord[e];
        const int   s = src[e];
        const float4 v = *(const float4*)(hw + (size_t)s * OUT_F + q * 4);
        acc.x = fmaf(o, v.x, acc.x);
        acc.y = fmaf(o, v.y, acc.y);
        acc.z = fmaf(o, v.z, acc.z);
        acc.w = fmaf(o, v.w, acc.w);
    }

    const float norm = 1.0f / fmaxf((float)deg, 1.0f);
    const float4 bb = *(const float4*)(b + q * 4);
    float4 r;
    r.x = fmaxf(fmaf(acc.x, norm, bb.x), 0.f);
    r.y = fmaxf(fmaf(acc.y, norm, bb.y), 0.f);
    r.z = fmaxf(fmaf(acc.z, norm, bb.z), 0.f);
    r.w = fmaxf(fmaf(acc.w, norm, bb.w), 0.f);
    *(float4*)(out + (size_t)n * OUT_F + q * 4) = r;
}

extern "C" void kernel_launch(void* const* d_in, const int* in_sizes, int n_in,
                              void* d_out, int out_size, void* d_ws, size_t ws_size,
                              hipStream_t stream) {
    const float* h   = (const float*)d_in[0];
    const int*   src = (const int*)  d_in[1];
    const int*   dst = (const int*)  d_in[2];
    const float* ord = (const float*)d_in[3];
    const float* W   = (const float*)d_in[4];
    const float* b   = (const float*)d_in[5];
    float*       out = (float*)d_out;

    // ws layout (20.0 MB total):
    //   hw     [N*32]  f32   12.8 MB   (16B aligned, offset 0)
    //   bucket [E]     i32    6.4 MB
    //   counts [N]     i32    0.4 MB
    //   offs   [N]     i32    0.4 MB
    //   gcur   [1]     i32
    float* ws     = (float*)d_ws;
    float* hw     = ws;
    int*   bucket = (int*)(ws + (size_t)N_NODES * OUT_F);
    int*   counts = bucket + N_EDGES;
    int*   offs   = counts + N_NODES;
    int*   gcur   = offs + N_NODES;

    // 1) hw = h @ W, zero counts/gcur
    hipLaunchKernelGGL(gemm64x32_zero, dim3(N_NODES / 8), dim3(256), 0, stream,
                       h, W, hw, counts, gcur);

    // 2) degree histogram
    hipLaunchKernelGGL(k_count, dim3(N_EDGES / 256), dim3(256), 0, stream,
                       dst, counts);

    // 3) bucket range allocation
    hipLaunchKernelGGL(k_alloc, dim3((N_NODES + 1023) / 1024), dim3(1024), 0, stream,
                       counts, offs, gcur);

    // 4) bin edges
    hipLaunchKernelGGL(k_bin, dim3(N_EDGES / 256), dim3(256), 0, stream,
                       dst, offs, bucket);

    // 5) gather + finalize
    hipLaunchKernelGGL(k_gather, dim3(N_NODES * 8 / 256), dim3(256), 0, stream,
                       bucket, offs, counts, src, ord, hw, b, out);
}